// Round 6
// baseline (121.950 us; speedup 1.0000x reference)
//
#include <hip/hip_runtime.h>
#include <hip/hip_bf16.h>

// S=8192, D_IN=512, D_OUT=64. O = softmax(tril(QK^T)/8) @ V.
// Round 24: attn de-staged. K/V tiles are L2/L1-resident (1MB each) and the
// MFMA fragment pattern is a clean per-lane global load -> LDS staging only
// burned the shared LDS pipe (24KB/wave-tile) + 2 sync points/tile + idle
// barrier rounds for causally-done waves. New attn: NO lds_k/lds_v, NO
// barriers, per-wave exact causal loop, direct global af/vf loads, 256-thr
// blocks x 544 (item x row-half) for 3-4 blocks/CU. P path byte-identical
// (per-wave LDS + lgkmcnt). proj reverted to R21 4-wave (best measured).
// Budget model: fill 43 (harness) + proj 13 + attn 36->~15 + reduce 9 + gaps.

typedef __attribute__((ext_vector_type(8))) short short8;   // 8 bf16 MFMA A/B frag
typedef __attribute__((ext_vector_type(4))) float f32x4;    // MFMA C/D frag
typedef __attribute__((ext_vector_type(4))) float f4v;
typedef __attribute__((ext_vector_type(2))) unsigned int u32x2;

__device__ inline unsigned int pk2(float a, float b) {
    union { __hip_bfloat162 h; unsigned int u; } v;
    v.h = __float22bfloat162_rn(make_float2(a, b));
    return v.u;
}

// Q-blocks of 256 rows (qb in [0,32)), parts of 512 cols. np(qb) = (qb>>1)+1.
// qb = 2a+b: base(qb) = a*a + a + b*(a+1). Total slots = 272.
__device__ inline int part_base(int qb) {
    int a = qb >> 1;
    return a * a + a + (qb & 1) * (a + 1);
}

// ---------------- QKV projection: x once in registers, mat-loop (R21/R18) ----------------
// grid 256, 256 thr (4 waves). Block: 32 x-rows. Wave w: row-group rg=w>>1
// (rows r0+rg*16..+15), n-half nh=w&1 (cols nh*32..+31). 64KB LDS -> 2 blocks/CU.
__global__ __launch_bounds__(256) void proj_kernel(const float* __restrict__ x,
                                                   const float* __restrict__ wq,
                                                   const float* __restrict__ wk,
                                                   const float* __restrict__ wv,
                                                   unsigned short* __restrict__ qbuf,
                                                   unsigned short* __restrict__ kbuf,
                                                   unsigned short* __restrict__ vt) {
    __shared__ unsigned short lds_w[64 * 512];   // 64KB bf16 W_mat, chunk^=(row&7)
    const int tid = threadIdx.x;
    const int wave = tid >> 6, lane = tid & 63;
    const int l16 = lane & 15, quad = lane >> 4;
    const int rg = wave >> 1, nh = wave & 1;
    const int r0 = blockIdx.x * 32;
    const int rw = r0 + rg * 16;                 // wave's 16 rows

    // x-frags ONCE into registers: xf[kc] = x[rw+l16][kc*32+quad*8..+7] (bf16)
    const float* xr = x + (rw + l16) * 512 + quad * 8;
    short8 xf[16];
#pragma unroll
    for (int kc = 0; kc < 16; ++kc) {
        f4v a0 = *(const f4v*)(xr + kc * 32);
        f4v a1 = *(const f4v*)(xr + kc * 32 + 4);
        union { short8 s8; unsigned int u[4]; } av;
        av.u[0] = pk2(a0.x, a0.y); av.u[1] = pk2(a0.z, a0.w);
        av.u[2] = pk2(a1.x, a1.y); av.u[3] = pk2(a1.z, a1.w);
        xf[kc] = av.s8;
    }

    for (int mat = 0; mat < 3; ++mat) {
        const float* wm = (mat == 0) ? wq : ((mat == 1) ? wk : wv);
        if (mat > 0) __syncthreads();            // all waves done reading lds_w

        // stage + convert W_mat: 4096 chunks of 8 bf16 (R15-identical)
#pragma unroll
        for (int j = 0; j < 16; ++j) {
            const int idx = j * 256 + tid;
            const int row = idx >> 6;
            const int gc = (idx & 63) ^ (row & 7);
            f4v v0 = *(const f4v*)(wm + row * 512 + gc * 8);
            f4v v1 = *(const f4v*)(wm + row * 512 + gc * 8 + 4);
            union { short8 s8; unsigned int u[4]; } pv;
            pv.u[0] = pk2(v0.x, v0.y); pv.u[1] = pk2(v0.z, v0.w);
            pv.u[2] = pk2(v1.x, v1.y); pv.u[3] = pk2(v1.z, v1.w);
            *(short8*)(lds_w + idx * 8) = pv.s8;
        }
        __syncthreads();

        // compute: wave's 2 n-tiles (rows of W = output cols nh*32..+31)
        f32x4 acc[2] = {};
#pragma unroll
        for (int kc = 0; kc < 16; ++kc) {
#pragma unroll
            for (int c = 0; c < 2; ++c) {
                short8 b = *(const short8*)(lds_w + ((nh * 2 + c) * 16 + l16) * 512 +
                                            (((kc * 4 + quad) ^ (l16 & 7)) * 8));
                acc[c] = __builtin_amdgcn_mfma_f32_16x16x32_bf16(xf[kc], b, acc[c], 0, 0, 0);
            }
        }

        const float scale = (mat == 0) ? 0.125f : 1.0f;   // fold 1/sqrt(d_k) into Q
#pragma unroll
        for (int c = 0; c < 2; ++c)
#pragma unroll
            for (int r = 0; r < 4; ++r) {
                const int row = rw + quad * 4 + r;   // C/D: row=(lane>>4)*4+reg, col=lane&15
                const int col = nh * 32 + c * 16 + l16;
                union { __hip_bfloat16 h; unsigned short u; } hv;
                hv.h = __float2bfloat16(acc[c][r] * scale);
                if (mat == 0)       qbuf[row * 64 + col] = hv.u;
                else if (mat == 1)  kbuf[row * 64 + col] = hv.u;
                else                vt[col * 8192 + row] = hv.u;   // V^T [64][8192]
            }
    }
}

// ---------------- barrier-free split-K flash attention, direct L2 loads ----------------
// grid 544 (item x half), 256 thr (4 waves). item 0..255 = 8-tile parts (qb asc),
// item 256..271 = even-qb diagonal 4-tile parts (last -> short tail).
// Wave = 32 Q-rows: q0 + half*128 + wave*32. No block-wide sync anywhere.
__global__ __launch_bounds__(256) void attn_kernel(const unsigned short* __restrict__ qbuf,
                                                   const unsigned short* __restrict__ kbuf,
                                                   const unsigned short* __restrict__ vt,
                                                   float* __restrict__ O_part,
                                                   float* __restrict__ l_part) {
    __shared__ unsigned short lds_p[4][32 * 72];  // per-wave P, stride 72  9KB

    const int bid = blockIdx.x;
    const int item = bid >> 1, half = bid & 1;
    int qb_i = 0, part = 0;
    if (item < 256) {
        int cum = 0;
        for (int qq = 1; qq < 32; ++qq) {
            const int aa = qq >> 1;
            const int cnt = (qq & 1) ? (aa + 1) : aa;   // big (8-tile) items in qq
            if (item < cum + cnt) { qb_i = qq; part = item - cum; break; }
            cum += cnt;
        }
    } else {
        qb_i = (item - 256) * 2;                  // even-qb diagonal, 4 tiles
        part = item - 256;
    }

    const int tid = threadIdx.x;
    const int wave = tid >> 6, lane = tid & 63;
    const int l16 = lane & 15, quad = lane >> 4;
    const int q0 = qb_i * 256;
    const int q0w = q0 + half * 128 + wave * 32;  // wave's 32 Q-rows
    const int c0 = part * 512;
    const int cend = min(c0 + 512, q0 + 256);     // 64-aligned
    unsigned short* lp = lds_p[wave];

    f32x4 o[2][4] = {};
    float ls[2] = {0.f, 0.f};

    short8 qf[2][2];
#pragma unroll
    for (int cg = 0; cg < 2; ++cg)
#pragma unroll
        for (int kg = 0; kg < 2; ++kg)
            qf[cg][kg] = *(const short8*)(qbuf + (q0w + cg * 16 + l16) * 64 + kg * 32 + quad * 8);

    const int wend = min(cend, q0w + 32);         // wave's exact causal tile range

    for (int kc0 = c0; kc0 < wend; kc0 += 64) {
        // K fragments direct from L2/L1 (same bytes the LDS path delivered)
        short8 af[4][2];
#pragma unroll
        for (int rg = 0; rg < 4; ++rg)
#pragma unroll
            for (int kg = 0; kg < 2; ++kg)
                af[rg][kg] = *(const short8*)(kbuf + (kc0 + rg * 16 + l16) * 64 +
                                              kg * 32 + quad * 8);

        // S^T = K Q^T: row=K-col kc0+rg*16+quad*4+r, col=Q-row q0w+cg*16+l16
        f32x4 st[4][2];
#pragma unroll
        for (int rg = 0; rg < 4; ++rg)
#pragma unroll
            for (int cg = 0; cg < 2; ++cg) {
                f32x4 z = {};
                z          = __builtin_amdgcn_mfma_f32_16x16x32_bf16(af[rg][0], qf[cg][0], z, 0, 0, 0);
                st[rg][cg] = __builtin_amdgcn_mfma_f32_16x16x32_bf16(af[rg][1], qf[cg][1], z, 0, 0, 0);
            }

        // V fragments (issue while MFMAs retire; independent)
        short8 vf[4][2];
#pragma unroll
        for (int ng = 0; ng < 4; ++ng)
#pragma unroll
            for (int kg = 0; kg < 2; ++kg)
                vf[ng][kg] = *(const short8*)(vt + (ng * 16 + l16) * 8192 +
                                              kc0 + kg * 32 + quad * 8);

        if (kc0 + 63 > q0w) {                     // diagonal tiles only
#pragma unroll
            for (int rg = 0; rg < 4; ++rg)
#pragma unroll
                for (int cg = 0; cg < 2; ++cg)
#pragma unroll
                    for (int r = 0; r < 4; ++r) {
                        const int kcol = kc0 + rg * 16 + quad * 4 + r;
                        const int qrow = q0w + cg * 16 + l16;
                        if (kcol > qrow) st[rg][cg][r] = -3.0e38f;
                    }
        }

        // p = exp(s), no max subtraction (r3-validated)
#pragma unroll
        for (int rg = 0; rg < 4; ++rg)
#pragma unroll
            for (int cg = 0; cg < 2; ++cg)
#pragma unroll
                for (int r = 0; r < 4; ++r) {
                    const float p = __expf(st[rg][cg][r]);
                    st[rg][cg][r] = p;
                    ls[cg] += p;
                }

        // P -> per-wave LDS, stride 72 (wave-synchronous, no barrier)
#pragma unroll
        for (int rg = 0; rg < 4; ++rg)
#pragma unroll
            for (int cg = 0; cg < 2; ++cg) {
                u32x2 w;
                w.x = pk2(st[rg][cg][0], st[rg][cg][1]);
                w.y = pk2(st[rg][cg][2], st[rg][cg][3]);
                *(u32x2*)(lp + (cg * 16 + l16) * 72 + rg * 16 + quad * 4) = w;
            }
        asm volatile("s_waitcnt lgkmcnt(0)" ::: "memory");
        short8 pa[2][2];
#pragma unroll
        for (int mg = 0; mg < 2; ++mg)
#pragma unroll
            for (int kg = 0; kg < 2; ++kg)
                pa[mg][kg] = *(const short8*)(lp + (mg * 16 + l16) * 72 + kg * 32 + quad * 8);

#pragma unroll
        for (int mg = 0; mg < 2; ++mg)
#pragma unroll
            for (int ng = 0; ng < 4; ++ng) {
                o[mg][ng] = __builtin_amdgcn_mfma_f32_16x16x32_bf16(pa[mg][0], vf[ng][0], o[mg][ng], 0, 0, 0);
                o[mg][ng] = __builtin_amdgcn_mfma_f32_16x16x32_bf16(pa[mg][1], vf[ng][1], o[mg][ng], 0, 0, 0);
            }
    }

#pragma unroll
    for (int cg = 0; cg < 2; ++cg) {
        ls[cg] += __shfl_xor(ls[cg], 16, 64);
        ls[cg] += __shfl_xor(ls[cg], 32, 64);
    }

    const int slot = part_base(qb_i) + part;
    float* Op = O_part + (size_t)slot * 16384;    // 256 rows x 64 cols
#pragma unroll
    for (int mg = 0; mg < 2; ++mg)
#pragma unroll
        for (int ng = 0; ng < 4; ++ng)
#pragma unroll
            for (int r = 0; r < 4; ++r)
                Op[(half * 128 + wave * 32 + mg * 16 + quad * 4 + r) * 64 + ng * 16 + l16] = o[mg][ng][r];
    if (quad == 0) {
#pragma unroll
        for (int cg = 0; cg < 2; ++cg)
            l_part[slot * 256 + half * 128 + wave * 32 + cg * 16 + l16] = ls[cg];
    }
}

// ---------------- combine: barrier-free, all loads in flight (R19) ----------------
__global__ __launch_bounds__(256) void attn_reduce_kernel(const float* __restrict__ O_part,
                                                          const float* __restrict__ l_part,
                                                          float* __restrict__ out) {
    const int qb_i = blockIdx.y;
    const int c = blockIdx.x;
    const int t = threadIdx.x;
    const int np = (qb_i >> 1) + 1;
    const int base = part_base(qb_i);

    // per-thread row-L: 16 unconditional loads (base+15 <= 271, always in-bounds),
    // masked add -> exact same sum order, one latency instead of a serial chain.
    const float* lrow = l_part + base * 256 + c * 16 + (t >> 4);
    float s = 0.0f;
#pragma unroll
    for (int p = 0; p < 16; ++p) {
        const float v = lrow[p * 256];
        s += (p < np) ? v : 0.0f;
    }

    const int e = c * 1024 + t * 4;               // element within slot / out tile
    const float* src = O_part + (size_t)base * 16384 + e;

    f4v a0 = {0.f, 0.f, 0.f, 0.f}, a1 = a0, a2 = a0, a3 = a0;
    f4v a4 = a0, a5 = a0, a6 = a0, a7 = a0;
    int p = 0;
    for (; p + 8 <= np; p += 8) {
        a0 += *(const f4v*)(src + (size_t)(p    ) * 16384);
        a1 += *(const f4v*)(src + (size_t)(p + 1) * 16384);
        a2 += *(const f4v*)(src + (size_t)(p + 2) * 16384);
        a3 += *(const f4v*)(src + (size_t)(p + 3) * 16384);
        a4 += *(const f4v*)(src + (size_t)(p + 4) * 16384);
        a5 += *(const f4v*)(src + (size_t)(p + 5) * 16384);
        a6 += *(const f4v*)(src + (size_t)(p + 6) * 16384);
        a7 += *(const f4v*)(src + (size_t)(p + 7) * 16384);
    }
    for (; p + 4 <= np; p += 4) {
        a0 += *(const f4v*)(src + (size_t)(p    ) * 16384);
        a1 += *(const f4v*)(src + (size_t)(p + 1) * 16384);
        a2 += *(const f4v*)(src + (size_t)(p + 2) * 16384);
        a3 += *(const f4v*)(src + (size_t)(p + 3) * 16384);
    }
    for (; p < np; ++p)
        a0 += *(const f4v*)(src + (size_t)p * 16384);

    f4v acc = ((a0 + a1) + (a2 + a3)) + ((a4 + a5) + (a6 + a7));
    acc *= (1.0f / s);
    *(f4v*)(out + (size_t)qb_i * 16384 + e) = acc;
}

extern "C" void kernel_launch(void* const* d_in, const int* in_sizes, int n_in,
                              void* d_out, int out_size, void* d_ws, size_t ws_size,
                              hipStream_t stream) {
    const float* x  = (const float*)d_in[0];
    const float* wq = (const float*)d_in[1];
    const float* wk = (const float*)d_in[2];
    const float* wv = (const float*)d_in[3];
    float* out = (float*)d_out;

    char* ws = (char*)d_ws;
    unsigned short* qb = (unsigned short*)(ws);               // 1,048,576 B
    unsigned short* kb = (unsigned short*)(ws + 1048576);     // 1,048,576 B
    unsigned short* vt = (unsigned short*)(ws + 2097152);     // 1,048,576 B (V^T [64][8192])
    float* O_part = (float*)(ws + 3145728);                   // 272*16384*4 = 17,825,792 B
    float* l_part = (float*)(ws + 20971520);                  // 272*256*4 = 278,528 B
    // total ws: 21,250,048 B

    proj_kernel<<<256, 256, 0, stream>>>(x, wq, wk, wv, qb, kb, vt);
    attn_kernel<<<544, 256, 0, stream>>>(qb, kb, vt, O_part, l_part);
    attn_reduce_kernel<<<dim3(16, 32), 256, 0, stream>>>(O_part, l_part, out);
}

// Round 7
// 119.192 us; speedup vs baseline: 1.0231x; 1.0231x over previous
//
#include <hip/hip_runtime.h>
#include <hip/hip_bf16.h>

// S=8192, D_IN=512, D_OUT=64. O = softmax(tril(QK^T)/8) @ V.
// Round 25: attn = barrier-free direct-load (R24 dataflow) + 2-deep register
// pipeline (afA/vfA <-> afB/vfB, unroll-by-2, static indexing per rule #20:
// no runtime-indexed frag arrays) + 1-wave blocks (grid 2176 = item x 8 subs,
// 64 thr, launch_bounds(64,2)). R24 counters showed 43.9us @ 6.8% MfmaUtil,
// 14.9% occupancy: per-tile serial chain = load-lat + compute with ~1 wave/SIMD.
// Pipeline makes it max(lat, compute); small blocks fix granularity/imbalance.
// proj = R21 (best measured ~13us), reduce = R19. P-path byte-identical.

typedef __attribute__((ext_vector_type(8))) short short8;   // 8 bf16 MFMA A/B frag
typedef __attribute__((ext_vector_type(4))) float f32x4;    // MFMA C/D frag
typedef __attribute__((ext_vector_type(4))) float f4v;
typedef __attribute__((ext_vector_type(2))) unsigned int u32x2;

__device__ inline unsigned int pk2(float a, float b) {
    union { __hip_bfloat162 h; unsigned int u; } v;
    v.h = __float22bfloat162_rn(make_float2(a, b));
    return v.u;
}

// Q-blocks of 256 rows (qb in [0,32)), parts of 512 cols. np(qb) = (qb>>1)+1.
// qb = 2a+b: base(qb) = a*a + a + b*(a+1). Total slots = 272.
__device__ inline int part_base(int qb) {
    int a = qb >> 1;
    return a * a + a + (qb & 1) * (a + 1);
}

// ---------------- QKV projection: x once in registers, mat-loop (R21/R18) ----------------
// grid 256, 256 thr (4 waves). Block: 32 x-rows. Wave w: row-group rg=w>>1
// (rows r0+rg*16..+15), n-half nh=w&1 (cols nh*32..+31). 64KB LDS -> 2 blocks/CU.
__global__ __launch_bounds__(256) void proj_kernel(const float* __restrict__ x,
                                                   const float* __restrict__ wq,
                                                   const float* __restrict__ wk,
                                                   const float* __restrict__ wv,
                                                   unsigned short* __restrict__ qbuf,
                                                   unsigned short* __restrict__ kbuf,
                                                   unsigned short* __restrict__ vt) {
    __shared__ unsigned short lds_w[64 * 512];   // 64KB bf16 W_mat, chunk^=(row&7)
    const int tid = threadIdx.x;
    const int wave = tid >> 6, lane = tid & 63;
    const int l16 = lane & 15, quad = lane >> 4;
    const int rg = wave >> 1, nh = wave & 1;
    const int r0 = blockIdx.x * 32;
    const int rw = r0 + rg * 16;                 // wave's 16 rows

    // x-frags ONCE into registers: xf[kc] = x[rw+l16][kc*32+quad*8..+7] (bf16)
    const float* xr = x + (rw + l16) * 512 + quad * 8;
    short8 xf[16];
#pragma unroll
    for (int kc = 0; kc < 16; ++kc) {
        f4v a0 = *(const f4v*)(xr + kc * 32);
        f4v a1 = *(const f4v*)(xr + kc * 32 + 4);
        union { short8 s8; unsigned int u[4]; } av;
        av.u[0] = pk2(a0.x, a0.y); av.u[1] = pk2(a0.z, a0.w);
        av.u[2] = pk2(a1.x, a1.y); av.u[3] = pk2(a1.z, a1.w);
        xf[kc] = av.s8;
    }

    for (int mat = 0; mat < 3; ++mat) {
        const float* wm = (mat == 0) ? wq : ((mat == 1) ? wk : wv);
        if (mat > 0) __syncthreads();            // all waves done reading lds_w

        // stage + convert W_mat: 4096 chunks of 8 bf16 (R15-identical)
#pragma unroll
        for (int j = 0; j < 16; ++j) {
            const int idx = j * 256 + tid;
            const int row = idx >> 6;
            const int gc = (idx & 63) ^ (row & 7);
            f4v v0 = *(const f4v*)(wm + row * 512 + gc * 8);
            f4v v1 = *(const f4v*)(wm + row * 512 + gc * 8 + 4);
            union { short8 s8; unsigned int u[4]; } pv;
            pv.u[0] = pk2(v0.x, v0.y); pv.u[1] = pk2(v0.z, v0.w);
            pv.u[2] = pk2(v1.x, v1.y); pv.u[3] = pk2(v1.z, v1.w);
            *(short8*)(lds_w + idx * 8) = pv.s8;
        }
        __syncthreads();

        // compute: wave's 2 n-tiles (rows of W = output cols nh*32..+31)
        f32x4 acc[2] = {};
#pragma unroll
        for (int kc = 0; kc < 16; ++kc) {
#pragma unroll
            for (int c = 0; c < 2; ++c) {
                short8 b = *(const short8*)(lds_w + ((nh * 2 + c) * 16 + l16) * 512 +
                                            (((kc * 4 + quad) ^ (l16 & 7)) * 8));
                acc[c] = __builtin_amdgcn_mfma_f32_16x16x32_bf16(xf[kc], b, acc[c], 0, 0, 0);
            }
        }

        const float scale = (mat == 0) ? 0.125f : 1.0f;   // fold 1/sqrt(d_k) into Q
#pragma unroll
        for (int c = 0; c < 2; ++c)
#pragma unroll
            for (int r = 0; r < 4; ++r) {
                const int row = rw + quad * 4 + r;   // C/D: row=(lane>>4)*4+reg, col=lane&15
                const int col = nh * 32 + c * 16 + l16;
                union { __hip_bfloat16 h; unsigned short u; } hv;
                hv.h = __float2bfloat16(acc[c][r] * scale);
                if (mat == 0)       qbuf[row * 64 + col] = hv.u;
                else if (mat == 1)  kbuf[row * 64 + col] = hv.u;
                else                vt[col * 8192 + row] = hv.u;   // V^T [64][8192]
            }
    }
}

// ---------------- barrier-free split-K flash attention, reg-pipelined ----------------
// grid 2176 (item x 8 subs), 64 thr (1 wave). item 0..255 = 8-tile parts (qb asc),
// item 256..271 = even-qb diagonal 4-tile parts. Wave = 32 Q-rows: q0 + sub*32.
// 2-deep register pipeline: tile t+1 af/vf loads issued before tile t compute.
__global__ __launch_bounds__(64, 2) void attn_kernel(const unsigned short* __restrict__ qbuf,
                                                     const unsigned short* __restrict__ kbuf,
                                                     const unsigned short* __restrict__ vt,
                                                     float* __restrict__ O_part,
                                                     float* __restrict__ l_part) {
    __shared__ unsigned short lds_p[32 * 72];     // per-wave P, stride 72  4.5KB

    const int bid = blockIdx.x;
    const int item = bid >> 3, sub = bid & 7;
    int qb_i = 0, part = 0;
    if (item < 256) {
        int cum = 0;
        for (int qq = 1; qq < 32; ++qq) {
            const int aa = qq >> 1;
            const int cnt = (qq & 1) ? (aa + 1) : aa;   // big (8-tile) items in qq
            if (item < cum + cnt) { qb_i = qq; part = item - cum; break; }
            cum += cnt;
        }
    } else {
        qb_i = (item - 256) * 2;                  // even-qb diagonal, 4 tiles
        part = item - 256;
    }

    const int lane = threadIdx.x & 63;
    const int l16 = lane & 15, quad = lane >> 4;
    const int q0 = qb_i * 256;
    const int q0w = q0 + sub * 32;                // wave's 32 Q-rows
    const int c0 = part * 512;
    const int cend = min(c0 + 512, q0 + 256);     // 64-aligned
    unsigned short* lp = lds_p;

    f32x4 o[2][4] = {};
    float ls[2] = {0.f, 0.f};

    short8 qf[2][2];
#pragma unroll
    for (int cg = 0; cg < 2; ++cg)
#pragma unroll
        for (int kg = 0; kg < 2; ++kg)
            qf[cg][kg] = *(const short8*)(qbuf + (q0w + cg * 16 + l16) * 64 + kg * 32 + quad * 8);

    const int wend = min(cend, q0w + 32);         // wave's exact causal tile range

    // fragment loaders / tile body (lambdas inline; arrays passed by reference
    // with compile-time indexing only -> stay in VGPRs)
    auto loadf = [&](short8 (&af)[4][2], short8 (&vf)[4][2], int kc0) {
#pragma unroll
        for (int rg = 0; rg < 4; ++rg)
#pragma unroll
            for (int kg = 0; kg < 2; ++kg) {
                af[rg][kg] = *(const short8*)(kbuf + (kc0 + rg * 16 + l16) * 64 +
                                              kg * 32 + quad * 8);
                vf[rg][kg] = *(const short8*)(vt + (rg * 16 + l16) * 8192 +
                                              kc0 + kg * 32 + quad * 8);
            }
    };

    auto body = [&](short8 (&af)[4][2], short8 (&vf)[4][2], int kc0) {
        // S^T = K Q^T: row=K-col kc0+rg*16+quad*4+r, col=Q-row q0w+cg*16+l16
        f32x4 st[4][2];
#pragma unroll
        for (int rg = 0; rg < 4; ++rg)
#pragma unroll
            for (int cg = 0; cg < 2; ++cg) {
                f32x4 z = {};
                z          = __builtin_amdgcn_mfma_f32_16x16x32_bf16(af[rg][0], qf[cg][0], z, 0, 0, 0);
                st[rg][cg] = __builtin_amdgcn_mfma_f32_16x16x32_bf16(af[rg][1], qf[cg][1], z, 0, 0, 0);
            }

        if (kc0 + 63 > q0w) {                     // diagonal tiles only
#pragma unroll
            for (int rg = 0; rg < 4; ++rg)
#pragma unroll
                for (int cg = 0; cg < 2; ++cg)
#pragma unroll
                    for (int r = 0; r < 4; ++r) {
                        const int kcol = kc0 + rg * 16 + quad * 4 + r;
                        const int qrow = q0w + cg * 16 + l16;
                        if (kcol > qrow) st[rg][cg][r] = -3.0e38f;
                    }
        }

        // p = exp(s), no max subtraction (r3-validated)
#pragma unroll
        for (int rg = 0; rg < 4; ++rg)
#pragma unroll
            for (int cg = 0; cg < 2; ++cg)
#pragma unroll
                for (int r = 0; r < 4; ++r) {
                    const float p = __expf(st[rg][cg][r]);
                    st[rg][cg][r] = p;
                    ls[cg] += p;
                }

        // P -> per-wave LDS, stride 72 (wave-synchronous, no barrier)
#pragma unroll
        for (int rg = 0; rg < 4; ++rg)
#pragma unroll
            for (int cg = 0; cg < 2; ++cg) {
                u32x2 w;
                w.x = pk2(st[rg][cg][0], st[rg][cg][1]);
                w.y = pk2(st[rg][cg][2], st[rg][cg][3]);
                *(u32x2*)(lp + (cg * 16 + l16) * 72 + rg * 16 + quad * 4) = w;
            }
        asm volatile("s_waitcnt lgkmcnt(0)" ::: "memory");
        short8 pa[2][2];
#pragma unroll
        for (int mg = 0; mg < 2; ++mg)
#pragma unroll
            for (int kg = 0; kg < 2; ++kg)
                pa[mg][kg] = *(const short8*)(lp + (mg * 16 + l16) * 72 + kg * 32 + quad * 8);

#pragma unroll
        for (int mg = 0; mg < 2; ++mg)
#pragma unroll
            for (int ng = 0; ng < 4; ++ng) {
                o[mg][ng] = __builtin_amdgcn_mfma_f32_16x16x32_bf16(pa[mg][0], vf[ng][0], o[mg][ng], 0, 0, 0);
                o[mg][ng] = __builtin_amdgcn_mfma_f32_16x16x32_bf16(pa[mg][1], vf[ng][1], o[mg][ng], 0, 0, 0);
            }
    };

    // 2-deep software pipeline, static A/B buffers (no runtime buf index)
    short8 afA[4][2], vfA[4][2], afB[4][2], vfB[4][2];
    int kc0 = c0;
    loadf(afA, vfA, kc0);
    while (true) {
        const bool hasB = (kc0 + 64 < wend);
        if (hasB) loadf(afB, vfB, kc0 + 64);      // issue next before computing cur
        body(afA, vfA, kc0);
        if (!hasB) break;
        kc0 += 64;
        const bool hasA = (kc0 + 64 < wend);
        if (hasA) loadf(afA, vfA, kc0 + 64);
        body(afB, vfB, kc0);
        if (!hasA) break;
        kc0 += 64;
    }

#pragma unroll
    for (int cg = 0; cg < 2; ++cg) {
        ls[cg] += __shfl_xor(ls[cg], 16, 64);
        ls[cg] += __shfl_xor(ls[cg], 32, 64);
    }

    const int slot = part_base(qb_i) + part;
    float* Op = O_part + (size_t)slot * 16384;    // 256 rows x 64 cols
#pragma unroll
    for (int mg = 0; mg < 2; ++mg)
#pragma unroll
        for (int ng = 0; ng < 4; ++ng)
#pragma unroll
            for (int r = 0; r < 4; ++r)
                Op[(sub * 32 + mg * 16 + quad * 4 + r) * 64 + ng * 16 + l16] = o[mg][ng][r];
    if (quad == 0) {
#pragma unroll
        for (int cg = 0; cg < 2; ++cg)
            l_part[slot * 256 + sub * 32 + cg * 16 + l16] = ls[cg];
    }
}

// ---------------- combine: barrier-free, all loads in flight (R19) ----------------
__global__ __launch_bounds__(256) void attn_reduce_kernel(const float* __restrict__ O_part,
                                                          const float* __restrict__ l_part,
                                                          float* __restrict__ out) {
    const int qb_i = blockIdx.y;
    const int c = blockIdx.x;
    const int t = threadIdx.x;
    const int np = (qb_i >> 1) + 1;
    const int base = part_base(qb_i);

    // per-thread row-L: 16 unconditional loads (base+15 <= 271, always in-bounds),
    // masked add -> exact same sum order, one latency instead of a serial chain.
    const float* lrow = l_part + base * 256 + c * 16 + (t >> 4);
    float s = 0.0f;
#pragma unroll
    for (int p = 0; p < 16; ++p) {
        const float v = lrow[p * 256];
        s += (p < np) ? v : 0.0f;
    }

    const int e = c * 1024 + t * 4;               // element within slot / out tile
    const float* src = O_part + (size_t)base * 16384 + e;

    f4v a0 = {0.f, 0.f, 0.f, 0.f}, a1 = a0, a2 = a0, a3 = a0;
    f4v a4 = a0, a5 = a0, a6 = a0, a7 = a0;
    int p = 0;
    for (; p + 8 <= np; p += 8) {
        a0 += *(const f4v*)(src + (size_t)(p    ) * 16384);
        a1 += *(const f4v*)(src + (size_t)(p + 1) * 16384);
        a2 += *(const f4v*)(src + (size_t)(p + 2) * 16384);
        a3 += *(const f4v*)(src + (size_t)(p + 3) * 16384);
        a4 += *(const f4v*)(src + (size_t)(p + 4) * 16384);
        a5 += *(const f4v*)(src + (size_t)(p + 5) * 16384);
        a6 += *(const f4v*)(src + (size_t)(p + 6) * 16384);
        a7 += *(const f4v*)(src + (size_t)(p + 7) * 16384);
    }
    for (; p + 4 <= np; p += 4) {
        a0 += *(const f4v*)(src + (size_t)(p    ) * 16384);
        a1 += *(const f4v*)(src + (size_t)(p + 1) * 16384);
        a2 += *(const f4v*)(src + (size_t)(p + 2) * 16384);
        a3 += *(const f4v*)(src + (size_t)(p + 3) * 16384);
    }
    for (; p < np; ++p)
        a0 += *(const f4v*)(src + (size_t)p * 16384);

    f4v acc = ((a0 + a1) + (a2 + a3)) + ((a4 + a5) + (a6 + a7));
    acc *= (1.0f / s);
    *(f4v*)(out + (size_t)qb_i * 16384 + e) = acc;
}

extern "C" void kernel_launch(void* const* d_in, const int* in_sizes, int n_in,
                              void* d_out, int out_size, void* d_ws, size_t ws_size,
                              hipStream_t stream) {
    const float* x  = (const float*)d_in[0];
    const float* wq = (const float*)d_in[1];
    const float* wk = (const float*)d_in[2];
    const float* wv = (const float*)d_in[3];
    float* out = (float*)d_out;

    char* ws = (char*)d_ws;
    unsigned short* qb = (unsigned short*)(ws);               // 1,048,576 B
    unsigned short* kb = (unsigned short*)(ws + 1048576);     // 1,048,576 B
    unsigned short* vt = (unsigned short*)(ws + 2097152);     // 1,048,576 B (V^T [64][8192])
    float* O_part = (float*)(ws + 3145728);                   // 272*16384*4 = 17,825,792 B
    float* l_part = (float*)(ws + 20971520);                  // 272*256*4 = 278,528 B
    // total ws: 21,250,048 B

    proj_kernel<<<256, 256, 0, stream>>>(x, wq, wk, wv, qb, kb, vt);
    attn_kernel<<<2176, 64, 0, stream>>>(qb, kb, vt, O_part, l_part);
    attn_reduce_kernel<<<dim3(16, 32), 256, 0, stream>>>(O_part, l_part, out);
}

// Round 8
// 99.301 us; speedup vs baseline: 1.2281x; 1.2003x over previous
//
#include <hip/hip_runtime.h>
#include <hip/hip_bf16.h>

// S=8192, D_IN=512, D_OUT=64. O = softmax(tril(QK^T)/8) @ V.
// Round 26: attn re-shaped for occupancy. R19-R25 all ran <=2 waves/SIMD
// (MfmaUtil ~7%, occ 13-15%) -- the chain was never hidden. This round: R21's
// staged/swizzled/barriered kernel EXACTLY, but 8 waves x 16 rows (was x32),
// grid 544 = item x row-half. Per-wave VGPR ~110 <= 128 -> launch_bounds(512,4)
// gives 2 blocks/CU = 16 waves/CU = 4 waves/SIMD; two independent blocks per CU
// cover each other's barrier/vmcnt stalls. proj/reduce byte-identical R21.

typedef __attribute__((ext_vector_type(8))) short short8;   // 8 bf16 MFMA A/B frag
typedef __attribute__((ext_vector_type(4))) float f32x4;    // MFMA C/D frag
typedef __attribute__((ext_vector_type(4))) float f4v;
typedef __attribute__((ext_vector_type(2))) unsigned int u32x2;

__device__ inline unsigned int pk2(float a, float b) {
    union { __hip_bfloat162 h; unsigned int u; } v;
    v.h = __float22bfloat162_rn(make_float2(a, b));
    return v.u;
}
__device__ inline void gload_lds16(const void* g, void* l) {
    __builtin_amdgcn_global_load_lds(
        (const __attribute__((address_space(1))) unsigned int*)g,
        (__attribute__((address_space(3))) unsigned int*)l, 16, 0, 0);
}

// Q-blocks of 256 rows (qb in [0,32)), parts of 512 cols. np(qb) = (qb>>1)+1.
// qb = 2a+b: base(qb) = a*a + a + b*(a+1). Total slots = 272.
__device__ inline int part_base(int qb) {
    int a = qb >> 1;
    return a * a + a + (qb & 1) * (a + 1);
}

// ---------------- QKV projection: x once in registers, mat-loop (R21/R18) ----------------
// grid 256, 256 thr (4 waves). Block: 32 x-rows. Wave w: row-group rg=w>>1
// (rows r0+rg*16..+15), n-half nh=w&1 (cols nh*32..+31). 64KB LDS -> 2 blocks/CU.
__global__ __launch_bounds__(256) void proj_kernel(const float* __restrict__ x,
                                                   const float* __restrict__ wq,
                                                   const float* __restrict__ wk,
                                                   const float* __restrict__ wv,
                                                   unsigned short* __restrict__ qbuf,
                                                   unsigned short* __restrict__ kbuf,
                                                   unsigned short* __restrict__ vt) {
    __shared__ unsigned short lds_w[64 * 512];   // 64KB bf16 W_mat, chunk^=(row&7)
    const int tid = threadIdx.x;
    const int wave = tid >> 6, lane = tid & 63;
    const int l16 = lane & 15, quad = lane >> 4;
    const int rg = wave >> 1, nh = wave & 1;
    const int r0 = blockIdx.x * 32;
    const int rw = r0 + rg * 16;                 // wave's 16 rows

    // x-frags ONCE into registers: xf[kc] = x[rw+l16][kc*32+quad*8..+7] (bf16)
    const float* xr = x + (rw + l16) * 512 + quad * 8;
    short8 xf[16];
#pragma unroll
    for (int kc = 0; kc < 16; ++kc) {
        f4v a0 = *(const f4v*)(xr + kc * 32);
        f4v a1 = *(const f4v*)(xr + kc * 32 + 4);
        union { short8 s8; unsigned int u[4]; } av;
        av.u[0] = pk2(a0.x, a0.y); av.u[1] = pk2(a0.z, a0.w);
        av.u[2] = pk2(a1.x, a1.y); av.u[3] = pk2(a1.z, a1.w);
        xf[kc] = av.s8;
    }

    for (int mat = 0; mat < 3; ++mat) {
        const float* wm = (mat == 0) ? wq : ((mat == 1) ? wk : wv);
        if (mat > 0) __syncthreads();            // all waves done reading lds_w

        // stage + convert W_mat: 4096 chunks of 8 bf16 (R15-identical)
#pragma unroll
        for (int j = 0; j < 16; ++j) {
            const int idx = j * 256 + tid;
            const int row = idx >> 6;
            const int gc = (idx & 63) ^ (row & 7);
            f4v v0 = *(const f4v*)(wm + row * 512 + gc * 8);
            f4v v1 = *(const f4v*)(wm + row * 512 + gc * 8 + 4);
            union { short8 s8; unsigned int u[4]; } pv;
            pv.u[0] = pk2(v0.x, v0.y); pv.u[1] = pk2(v0.z, v0.w);
            pv.u[2] = pk2(v1.x, v1.y); pv.u[3] = pk2(v1.z, v1.w);
            *(short8*)(lds_w + idx * 8) = pv.s8;
        }
        __syncthreads();

        // compute: wave's 2 n-tiles (rows of W = output cols nh*32..+31)
        f32x4 acc[2] = {};
#pragma unroll
        for (int kc = 0; kc < 16; ++kc) {
#pragma unroll
            for (int c = 0; c < 2; ++c) {
                short8 b = *(const short8*)(lds_w + ((nh * 2 + c) * 16 + l16) * 512 +
                                            (((kc * 4 + quad) ^ (l16 & 7)) * 8));
                acc[c] = __builtin_amdgcn_mfma_f32_16x16x32_bf16(xf[kc], b, acc[c], 0, 0, 0);
            }
        }

        const float scale = (mat == 0) ? 0.125f : 1.0f;   // fold 1/sqrt(d_k) into Q
#pragma unroll
        for (int c = 0; c < 2; ++c)
#pragma unroll
            for (int r = 0; r < 4; ++r) {
                const int row = rw + quad * 4 + r;   // C/D: row=(lane>>4)*4+reg, col=lane&15
                const int col = nh * 32 + c * 16 + l16;
                union { __hip_bfloat16 h; unsigned short u; } hv;
                hv.h = __float2bfloat16(acc[c][r] * scale);
                if (mat == 0)       qbuf[row * 64 + col] = hv.u;
                else if (mat == 1)  kbuf[row * 64 + col] = hv.u;
                else                vt[col * 8192 + row] = hv.u;   // V^T [64][8192]
            }
    }
}

// ---------------- staged split-K flash attention, 16-row waves, 4 waves/SIMD ----------------
// grid 544 = item x row-half, 512 thr (8 waves x 16 Q-rows). Blocks 0..511 =
// 8-tile items (qb ascending), 512..543 = even-qb diagonal 4-tile items (last).
// launch_bounds(512,4): VGPR<=128 -> 2 blocks/CU = 16 waves/CU.
__global__ __launch_bounds__(512, 4) void attn_kernel(const unsigned short* __restrict__ qbuf,
                                                      const unsigned short* __restrict__ kbuf,
                                                      const unsigned short* __restrict__ vt,
                                                      float* __restrict__ O_part,
                                                      float* __restrict__ l_part) {
    __shared__ unsigned short lds_k[2][64 * 64];  // [buf][row][64], chunk^=(row&7) 16KB
    __shared__ unsigned short lds_v[2][64 * 64];  // V^T tile [buf][dim][64]        16KB
    __shared__ unsigned short lds_p[8][16 * 72];  // per-wave P (16 rows), stride 72 18KB

    const int bid = blockIdx.x;
    const int item = bid >> 1, half = bid & 1;
    int qb_i = 0, part = 0;
    if (item < 256) {
        int cum = 0;
        for (int qq = 1; qq < 32; ++qq) {
            const int aa = qq >> 1;
            const int cnt = (qq & 1) ? (aa + 1) : aa;   // big (8-tile) items in qq
            if (item < cum + cnt) { qb_i = qq; part = item - cum; break; }
            cum += cnt;
        }
    } else {
        qb_i = (item - 256) * 2;                  // even-qb diagonal, 4 tiles
        part = item - 256;
    }

    const int tid = threadIdx.x;
    const int wave = tid >> 6, lane = tid & 63;
    const int l16 = lane & 15, quad = lane >> 4;
    const int q0 = qb_i * 256;
    const int q0w = q0 + half * 128 + wave * 16;  // wave's 16 Q-rows
    const int c0 = part * 512;
    const int cend = min(c0 + 512, q0 + 256);     // 64-aligned
    const int ntiles = (cend - c0) >> 6;          // 4 or 8
    unsigned short* lp = lds_p[wave];

    f32x4 o[4] = {};
    float ls = 0.f;

    short8 qf[2];
#pragma unroll
    for (int kg = 0; kg < 2; ++kg)
        qf[kg] = *(const short8*)(qbuf + (q0w + l16) * 64 + kg * 32 + quad * 8);

    const int sidx = tid;
    const int srow = sidx >> 3;
    const int scc = (sidx & 7) ^ (srow & 7);

    // prologue: issue tile 0 staging into buf 0 (no barrier; loop head syncs)
    gload_lds16(kbuf + (c0 + srow) * 64 + scc * 8, lds_k[0] + sidx * 8);
    gload_lds16(vt + srow * 8192 + c0 + scc * 8,   lds_v[0] + sidx * 8);

    int cur = 0;
    for (int it = 0; it < ntiles; ++it) {
        // own tile-it staging retired (covered by previous tile's compute) ...
        asm volatile("s_waitcnt vmcnt(0)" ::: "memory");
        // ... then everyone's: all of buf[cur] valid, all reads of buf[cur^1] done
        __builtin_amdgcn_s_barrier();
        __builtin_amdgcn_sched_barrier(0);

        // issue next-tile staging NOW: latency hides under this tile's compute
        if (it + 1 < ntiles) {
            const int kn = c0 + (it + 1) * 64;
            gload_lds16(kbuf + (kn + srow) * 64 + scc * 8, lds_k[cur ^ 1] + sidx * 8);
            gload_lds16(vt + srow * 8192 + kn + scc * 8,   lds_v[cur ^ 1] + sidx * 8);
        }

        const int kc0 = c0 + it * 64;
        if (kc0 <= q0w + 15) {                    // wave-uniform compute guard
            // S^T = K Q^T: row=K-col kc0+rg*16+quad*4+r, col=Q-row q0w+l16
            f32x4 st[4];
#pragma unroll
            for (int rg = 0; rg < 4; ++rg) {
                short8 a0 = *(const short8*)(lds_k[cur] + (rg * 16 + l16) * 64 +
                                             ((quad ^ (l16 & 7)) * 8));
                short8 a1 = *(const short8*)(lds_k[cur] + (rg * 16 + l16) * 64 +
                                             (((4 + quad) ^ (l16 & 7)) * 8));
                f32x4 z = {};
                z      = __builtin_amdgcn_mfma_f32_16x16x32_bf16(a0, qf[0], z, 0, 0, 0);
                st[rg] = __builtin_amdgcn_mfma_f32_16x16x32_bf16(a1, qf[1], z, 0, 0, 0);
            }

            if (kc0 + 63 > q0w) {                 // diagonal tiles only
#pragma unroll
                for (int rg = 0; rg < 4; ++rg)
#pragma unroll
                    for (int r = 0; r < 4; ++r) {
                        const int kcol = kc0 + rg * 16 + quad * 4 + r;
                        const int qrow = q0w + l16;
                        if (kcol > qrow) st[rg][r] = -3.0e38f;
                    }
            }

            // p = exp(s), no max subtraction (r3-validated)
#pragma unroll
            for (int rg = 0; rg < 4; ++rg)
#pragma unroll
                for (int r = 0; r < 4; ++r) {
                    const float p = __expf(st[rg][r]);
                    st[rg][r] = p;
                    ls += p;
                }

            // P -> per-wave LDS, stride 72 (wave-synchronous)
#pragma unroll
            for (int rg = 0; rg < 4; ++rg) {
                u32x2 w;
                w.x = pk2(st[rg][0], st[rg][1]);
                w.y = pk2(st[rg][2], st[rg][3]);
                *(u32x2*)(lp + l16 * 72 + rg * 16 + quad * 4) = w;
            }
            asm volatile("s_waitcnt lgkmcnt(0)" ::: "memory");
            short8 pa[2];
#pragma unroll
            for (int kg = 0; kg < 2; ++kg)
                pa[kg] = *(const short8*)(lp + l16 * 72 + kg * 32 + quad * 8);

#pragma unroll
            for (int ng = 0; ng < 4; ++ng) {
                short8 v0 = *(const short8*)(lds_v[cur] + (ng * 16 + l16) * 64 +
                                             ((quad ^ (l16 & 7)) * 8));
                short8 v1 = *(const short8*)(lds_v[cur] + (ng * 16 + l16) * 64 +
                                             (((4 + quad) ^ (l16 & 7)) * 8));
                o[ng] = __builtin_amdgcn_mfma_f32_16x16x32_bf16(pa[0], v0, o[ng], 0, 0, 0);
                o[ng] = __builtin_amdgcn_mfma_f32_16x16x32_bf16(pa[1], v1, o[ng], 0, 0, 0);
            }
        }
        cur ^= 1;
    }

    ls += __shfl_xor(ls, 16, 64);
    ls += __shfl_xor(ls, 32, 64);

    const int slot = part_base(qb_i) + part;
    const int rbase = half * 128 + wave * 16;
    float* Op = O_part + (size_t)slot * 16384;    // 256 rows x 64 cols
#pragma unroll
    for (int ng = 0; ng < 4; ++ng)
#pragma unroll
        for (int r = 0; r < 4; ++r)
            Op[(rbase + quad * 4 + r) * 64 + ng * 16 + l16] = o[ng][r];
    if (quad == 0)
        l_part[slot * 256 + rbase + l16] = ls;
}

// ---------------- combine: barrier-free, all loads in flight (R19) ----------------
__global__ __launch_bounds__(256) void attn_reduce_kernel(const float* __restrict__ O_part,
                                                          const float* __restrict__ l_part,
                                                          float* __restrict__ out) {
    const int qb_i = blockIdx.y;
    const int c = blockIdx.x;
    const int t = threadIdx.x;
    const int np = (qb_i >> 1) + 1;
    const int base = part_base(qb_i);

    // per-thread row-L: 16 unconditional loads (base+15 <= 271, always in-bounds),
    // masked add -> exact same sum order, one latency instead of a serial chain.
    const float* lrow = l_part + base * 256 + c * 16 + (t >> 4);
    float s = 0.0f;
#pragma unroll
    for (int p = 0; p < 16; ++p) {
        const float v = lrow[p * 256];
        s += (p < np) ? v : 0.0f;
    }

    const int e = c * 1024 + t * 4;               // element within slot / out tile
    const float* src = O_part + (size_t)base * 16384 + e;

    f4v a0 = {0.f, 0.f, 0.f, 0.f}, a1 = a0, a2 = a0, a3 = a0;
    f4v a4 = a0, a5 = a0, a6 = a0, a7 = a0;
    int p = 0;
    for (; p + 8 <= np; p += 8) {
        a0 += *(const f4v*)(src + (size_t)(p    ) * 16384);
        a1 += *(const f4v*)(src + (size_t)(p + 1) * 16384);
        a2 += *(const f4v*)(src + (size_t)(p + 2) * 16384);
        a3 += *(const f4v*)(src + (size_t)(p + 3) * 16384);
        a4 += *(const f4v*)(src + (size_t)(p + 4) * 16384);
        a5 += *(const f4v*)(src + (size_t)(p + 5) * 16384);
        a6 += *(const f4v*)(src + (size_t)(p + 6) * 16384);
        a7 += *(const f4v*)(src + (size_t)(p + 7) * 16384);
    }
    for (; p + 4 <= np; p += 4) {
        a0 += *(const f4v*)(src + (size_t)(p    ) * 16384);
        a1 += *(const f4v*)(src + (size_t)(p + 1) * 16384);
        a2 += *(const f4v*)(src + (size_t)(p + 2) * 16384);
        a3 += *(const f4v*)(src + (size_t)(p + 3) * 16384);
    }
    for (; p < np; ++p)
        a0 += *(const f4v*)(src + (size_t)p * 16384);

    f4v acc = ((a0 + a1) + (a2 + a3)) + ((a4 + a5) + (a6 + a7));
    acc *= (1.0f / s);
    *(f4v*)(out + (size_t)qb_i * 16384 + e) = acc;
}

extern "C" void kernel_launch(void* const* d_in, const int* in_sizes, int n_in,
                              void* d_out, int out_size, void* d_ws, size_t ws_size,
                              hipStream_t stream) {
    const float* x  = (const float*)d_in[0];
    const float* wq = (const float*)d_in[1];
    const float* wk = (const float*)d_in[2];
    const float* wv = (const float*)d_in[3];
    float* out = (float*)d_out;

    char* ws = (char*)d_ws;
    unsigned short* qb = (unsigned short*)(ws);               // 1,048,576 B
    unsigned short* kb = (unsigned short*)(ws + 1048576);     // 1,048,576 B
    unsigned short* vt = (unsigned short*)(ws + 2097152);     // 1,048,576 B (V^T [64][8192])
    float* O_part = (float*)(ws + 3145728);                   // 272*16384*4 = 17,825,792 B
    float* l_part = (float*)(ws + 20971520);                  // 272*256*4 = 278,528 B
    // total ws: 21,250,048 B

    proj_kernel<<<256, 256, 0, stream>>>(x, wq, wk, wv, qb, kb, vt);
    attn_kernel<<<544, 512, 0, stream>>>(qb, kb, vt, O_part, l_part);
    attn_reduce_kernel<<<dim3(16, 32), 256, 0, stream>>>(O_part, l_part, out);
}